// Round 13
// baseline (711.106 us; speedup 1.0000x reference)
//
#include <hip/hip_runtime.h>
#include <hip/hip_bf16.h>
#include <cstddef>

#define NA 50000
#define NP 100000
#define NE 200000
#define SCAN_CHUNK 1024

typedef unsigned short u16;
typedef unsigned int u32;
typedef short v8s __attribute__((ext_vector_type(8)));
typedef float f32x4 __attribute__((ext_vector_type(4)));

union U8 { uint4 q; v8s v; };

__device__ __forceinline__ float elu_f(float x) {
  return x > 0.0f ? x : expm1f(x);
}
__device__ __forceinline__ u16 f2bf(float x) {
  u32 u = __float_as_uint(x);
  return (u16)((u + 0x7fffu + ((u >> 16) & 1u)) >> 16);
}
__device__ __forceinline__ float bf2f(u16 h) {
  return __uint_as_float(((u32)h) << 16);
}
__device__ __forceinline__ u32 pk2(float a, float b) {
  return (u32)f2bf(a) | ((u32)f2bf(b) << 16);
}
__device__ __forceinline__ float lo_f(u32 w) { return __uint_as_float(w << 16); }
__device__ __forceinline__ float hi_f(u32 w) { return __uint_as_float(w & 0xffff0000u); }

// async global->LDS, 16B per lane; ldst must be wave-uniform (HW adds lane*16)
__device__ __forceinline__ void gload_lds16(const u16* gsrc, u16* ldst) {
  __builtin_amdgcn_global_load_lds(
      (const __attribute__((address_space(1))) u32*)gsrc,
      (__attribute__((address_space(3))) u32*)ldst, 16, 0, 0);
}

// ---------------- degree counting (int) ----------------
__global__ void count_deg_i(const int* __restrict__ dst_p, const int* __restrict__ dst_a,
                            int* cnt_p, int* cnt_a) {
  int i = blockIdx.x * blockDim.x + threadIdx.x;
  if (i < NE) atomicAdd(&cnt_p[dst_p[i]], 1);
  else if (i < 2 * NE) atomicAdd(&cnt_a[dst_a[i - NE]], 1);
}

// ---------------- 3-kernel exclusive scan ----------------
__global__ void block_sums_k(const int* __restrict__ cnt, int* __restrict__ bsums, int n) {
  __shared__ int red[256];
  int t = threadIdx.x;
  int base = blockIdx.x * SCAN_CHUNK + t * 4;
  int s = 0;
  #pragma unroll
  for (int i = 0; i < 4; ++i) {
    int idx = base + i;
    if (idx < n) s += cnt[idx];
  }
  red[t] = s;
  __syncthreads();
  for (int off = 128; off > 0; off >>= 1) {
    if (t < off) red[t] += red[t + off];
    __syncthreads();
  }
  if (t == 0) bsums[blockIdx.x] = red[0];
}

__global__ void scan_bsums_k(int* bsums, int nb) {  // nb <= 256, single block
  __shared__ int tmp[256];
  int t = threadIdx.x;
  int orig = (t < nb) ? bsums[t] : 0;
  tmp[t] = orig;
  __syncthreads();
  for (int off = 1; off < 256; off <<= 1) {
    int u = (t >= off) ? tmp[t - off] : 0;
    __syncthreads();
    tmp[t] += u;
    __syncthreads();
  }
  if (t < nb) bsums[t] = tmp[t] - orig;  // exclusive
}

// writes row_start AND cursor copy
__global__ void scan_final_k(const int* __restrict__ cnt, const int* __restrict__ bsums,
                             int* __restrict__ row_start, int* __restrict__ cursor,
                             int n, int total) {
  __shared__ int red[256];
  int t = threadIdx.x;
  int base = blockIdx.x * SCAN_CHUNK + t * 4;
  int v[4];
  int s = 0;
  #pragma unroll
  for (int i = 0; i < 4; ++i) {
    int idx = base + i;
    v[i] = (idx < n) ? cnt[idx] : 0;
    s += v[i];
  }
  int orig = s;
  red[t] = s;
  __syncthreads();
  for (int off = 1; off < 256; off <<= 1) {
    int u = (t >= off) ? red[t - off] : 0;
    __syncthreads();
    red[t] += u;
    __syncthreads();
  }
  int excl = red[t] - orig + bsums[blockIdx.x];
  #pragma unroll
  for (int i = 0; i < 4; ++i) {
    int idx = base + i;
    if (idx < n) {
      row_start[idx] = excl;
      cursor[idx] = excl;
    }
    excl += v[i];
  }
  if (blockIdx.x == 0 && t == 0) row_start[n] = total;
}

__global__ void csr_fill(const int* __restrict__ src, const int* __restrict__ dst,
                         int* cursor, int* __restrict__ csr_src) {
  int e = blockIdx.x * blockDim.x + threadIdx.x;
  if (e < NE) {
    int p = atomicAdd(&cursor[dst[e]], 1);
    csr_src[p] = src[e];
  }
}

// ---------------- f32 -> bf16 bulk convert ----------------
__global__ void to_bf16(const float* __restrict__ in, u16* __restrict__ out, int n4) {
  int i = blockIdx.x * 256 + threadIdx.x;
  if (i >= n4) return;
  float4 v = ((const float4*)in)[i];
  uint2 o;
  o.x = pk2(v.x, v.y);
  o.y = pk2(v.z, v.w);
  *(uint2*)(out + (size_t)i * 4) = o;
}

// ---------------- weight pack (all matrices, one launch) ----------------
// W: [256][K] f32 -> Wp[ks][c 16][lane 64][8] bf16   (16 KB per 32-K chunk)
struct PackJobs {
  const float* src[12];
  u16* dst[12];
  int K[12];
  int boff[13];
};

__global__ void pack_all(PackJobs J) {
  int blk = blockIdx.x;
  int j = 0;
  while (j < 11 && blk >= J.boff[j + 1]) ++j;
  int id = (blk - J.boff[j]) * 256 + threadIdx.x;  // < K*32 exactly
  int K = J.K[j];
  int l = id & 63;
  int c = (id >> 6) & 15;
  int ks = id >> 10;
  int n = c * 16 + (l & 15);
  int k = ks * 32 + (l >> 4) * 8;
  const float* src = J.src[j] + (size_t)n * K + k;
  uint4 o;
  o.x = pk2(src[0], src[1]);
  o.y = pk2(src[2], src[3]);
  o.z = pk2(src[4], src[5]);
  o.w = pk2(src[6], src[7]);
  *(uint4*)(J.dst[j] + (size_t)id * 8) = o;
}

// ---------------- bias combine (all 6, one launch) ----------------
struct BiasJobs {
  const float* a[6];
  const float* b[6];
  float* o[6];
};
__global__ void bias_all(BiasJobs J) {
  int j = blockIdx.x;
  int i = threadIdx.x;
  J.o[j][i] = J.a[j][i] + J.b[j][i];
}

// ---------------- FUSED gather-mean + SAGE GEMM, bf16 MFMA ----------------
// out[i,:] = elu( mean_{j in N(i)} feat[j,:] @ Wl^T + x[i,:] @ Wr^T + bias )
// Wp packed [Wl|Wr] chunk-major. Block: 512 thr = 8 waves (4 rw x 2 cw);
// tile = 128 rows x 256 cols (full width -> 512 B/row contiguous writes, x rows
// read once). Wave: 32 rows (2 rt x 16) x 128 cols (8 ctiles), acc[2][8].
// Phase 1 (chunks < nk1): A-operand fragments gathered DIRECTLY from CSR edges
// into f32 registers per 32-K chunk (agg buffer never materialized; cw-pair
// duplicate gather hits L1/L2). Phase 2: x streamed with 1-chunk prefetch.
// Weights: 16 KB/chunk DMA'd via global_load_lds into 2-buffer LDS, staged one
// chunk ahead; phase-2 end-of-stage sync = counted vmcnt(2) (x stays in flight).
struct SideF {
  const u16* feat;   // gather source features (K1 wide)
  const int* cs;     // CSR src indices grouped by dst
  const int* rs;     // CSR row_start per dst node
  const u16* x;      // dst features (K2 wide)
  const u16* Wp;     // packed [Wl|Wr], (K1+K2)*256 u16
  const float* bias;
  u16* out;
  int M;
  int K1;
  int K2;
};

__global__ __launch_bounds__(512, 4) void sage_fgem(SideF P, SideF A, int nbP) {
  __shared__ __align__(16) u16 ldsw[2][8192];  // 2 x 16 KB
  SideF S;
  int bid = blockIdx.x;
  if (bid < nbP) { S = P; } else { bid -= nbP; S = A; }

  const int nk1 = S.K1 >> 5;
  const int nk = nk1 + (S.K2 >> 5);
  const int t = threadIdx.x;
  const int w = t >> 6, l = t & 63;
  const int rw = w & 3, cw = w >> 2;
  const int lr = l & 15, lk = l >> 4;
  const int row0 = bid * 128 + rw * 32 + lr;
  const int row1 = row0 + 16;
  const int ar0 = min(row0, S.M - 1);
  const int ar1 = min(row1, S.M - 1);
  const int beg0 = S.rs[ar0], end0 = S.rs[ar0 + 1];
  const int beg1 = S.rs[ar1], end1 = S.rs[ar1 + 1];
  const float inv0 = 1.0f / fmaxf((float)(end0 - beg0), 1.0f);
  const float inv1 = 1.0f / fmaxf((float)(end1 - beg1), 1.0f);
  const u16* px0 = S.x + (size_t)ar0 * S.K2 + lk * 8;
  const u16* px1 = S.x + (size_t)ar1 * S.K2 + lk * 8;

  // stage weight chunk c into LDS buffer b (2 DMA rounds, 512 thr x 16 B)
  auto wstage = [&](int c, int b) {
    const u16* g = S.Wp + (size_t)c * 8192 + (size_t)t * 8;
    u16* d = ldsw[b] + w * 512;  // wave-uniform base; HW adds lane*16
    gload_lds16(g, d);
    gload_lds16(g + 4096, d + 4096);
  };
  // gather one A-fragment: mean over edges of rows' chunk-c columns
  auto gfrag = [&](int c, int beg, int end, float inv) -> v8s {
    const u16* fb = S.feat + c * 32 + lk * 8;
    float a0 = 0.f, a1 = 0.f, a2 = 0.f, a3 = 0.f;
    float a4 = 0.f, a5 = 0.f, a6 = 0.f, a7 = 0.f;
    for (int e = beg; e < end; ++e) {
      uint4 u = *(const uint4*)(fb + (size_t)S.cs[e] * S.K1);
      a0 += lo_f(u.x); a1 += hi_f(u.x);
      a2 += lo_f(u.y); a3 += hi_f(u.y);
      a4 += lo_f(u.z); a5 += hi_f(u.z);
      a6 += lo_f(u.w); a7 += hi_f(u.w);
    }
    U8 r;
    r.q.x = pk2(a0 * inv, a1 * inv);
    r.q.y = pk2(a2 * inv, a3 * inv);
    r.q.z = pk2(a4 * inv, a5 * inv);
    r.q.w = pk2(a6 * inv, a7 * inv);
    return r.v;
  };

  f32x4 acc[2][8];
  #pragma unroll
  for (int rt = 0; rt < 2; ++rt)
    #pragma unroll
    for (int i = 0; i < 8; ++i) acc[rt][i] = (f32x4){0.f, 0.f, 0.f, 0.f};

  // prologue: stage chunk 0; preload phase-2 first x fragments (drained by the
  // prologue vmcnt(0), values parked in regs until phase 2)
  wstage(0, 0);
  v8s xc0 = *(const v8s*)px0;
  v8s xc1 = *(const v8s*)px1;
  asm volatile("s_waitcnt vmcnt(0)" ::: "memory");
  __builtin_amdgcn_s_barrier();

  // ---- phase 1: gathered-A chunks ----
  for (int c = 0; c < nk1; ++c) {
    if (c + 1 < nk) wstage(c + 1, (c + 1) & 1);
    v8s af0 = gfrag(c, beg0, end0, inv0);
    v8s af1 = gfrag(c, beg1, end1, inv1);
    const u16* lw = ldsw[c & 1] + cw * 4096 + (size_t)l * 8;
    #pragma unroll
    for (int i = 0; i < 8; ++i) {
      v8s wf = *(const v8s*)(lw + i * 512);
      acc[0][i] = __builtin_amdgcn_mfma_f32_16x16x32_bf16(wf, af0, acc[0][i], 0, 0, 0);
      acc[1][i] = __builtin_amdgcn_mfma_f32_16x16x32_bf16(wf, af1, acc[1][i], 0, 0, 0);
    }
    // drain (covers w-DMA even when deg==0); then publish buffer swap
    asm volatile("s_waitcnt vmcnt(0)" ::: "memory");
    __builtin_amdgcn_s_barrier();
  }

  // ---- phase 2: x chunks, 1-ahead prefetch, counted vmcnt ----
  for (int c = nk1; c < nk; ++c) {
    const bool more = (c + 1 < nk);
    v8s xn0, xn1;
    if (more) {
      wstage(c + 1, (c + 1) & 1);  // 2 VMEM ops (oldest)
      const int off = (c + 1 - nk1) * 32;
      xn0 = *(const v8s*)(px0 + off);  // 2 VMEM ops (newest)
      xn1 = *(const v8s*)(px1 + off);
    }
    const u16* lw = ldsw[c & 1] + cw * 4096 + (size_t)l * 8;
    #pragma unroll
    for (int i = 0; i < 8; ++i) {
      v8s wf = *(const v8s*)(lw + i * 512);
      acc[0][i] = __builtin_amdgcn_mfma_f32_16x16x32_bf16(wf, xc0, acc[0][i], 0, 0, 0);
      acc[1][i] = __builtin_amdgcn_mfma_f32_16x16x32_bf16(wf, xc1, acc[1][i], 0, 0, 0);
    }
    if (more) {
      // w-DMA (older) done; keep the 2 x prefetches in flight across barrier
      asm volatile("s_waitcnt vmcnt(2)" ::: "memory");
      __builtin_amdgcn_s_barrier();
      xc0 = xn0;
      xc1 = xn1;
    }
  }

  // epilogue: bias + ELU + bf16 store (full 512 B/row across block)
  const int colb = cw * 128 + lk * 4;
  #pragma unroll
  for (int rt = 0; rt < 2; ++rt) {
    const int row = rt == 0 ? row0 : row1;
    if (row < S.M) {
      u16* orow = S.out + (size_t)row * 256 + colb;
      #pragma unroll
      for (int i = 0; i < 8; ++i) {
        f32x4 bv = *(const f32x4*)(S.bias + colb + i * 16);
        float e0 = elu_f(acc[rt][i][0] + bv[0]);
        float e1 = elu_f(acc[rt][i][1] + bv[1]);
        float e2 = elu_f(acc[rt][i][2] + bv[2]);
        float e3 = elu_f(acc[rt][i][3] + bv[3]);
        uint2 o;
        o.x = pk2(e0, e1);
        o.y = pk2(e2, e3);
        *(uint2*)(orow + i * 16) = o;
      }
    }
  }
}

// ---------------- output projection (bf16 author) ----------------
__global__ __launch_bounds__(256) void out_proj(const u16* __restrict__ author,
                                                const float* __restrict__ W,
                                                const float* __restrict__ b,
                                                float* __restrict__ out, int M) {
  __shared__ float ws[10 * 256];
  __shared__ float bs[10];
  int t = threadIdx.x;
  for (int i = t; i < 2560; i += 256) ws[i] = W[i];
  if (t < 10) bs[t] = b[t];
  __syncthreads();
  int wave = t >> 6, lane = t & 63;
  int row = blockIdx.x * 4 + wave;
  if (row >= M) return;
  ushort4 u = *(const ushort4*)(author + (size_t)row * 256 + lane * 4);
  float a0 = bf2f(u.x), a1 = bf2f(u.y), a2 = bf2f(u.z), a3 = bf2f(u.w);
  float p[10];
  #pragma unroll
  for (int n = 0; n < 10; ++n) {
    const float* wv = ws + n * 256 + lane * 4;
    p[n] = a0 * wv[0] + a1 * wv[1] + a2 * wv[2] + a3 * wv[3];
  }
  #pragma unroll
  for (int off = 32; off > 0; off >>= 1) {
    #pragma unroll
    for (int n = 0; n < 10; ++n) p[n] += __shfl_down(p[n], off);
  }
  if (lane == 0) {
    #pragma unroll
    for (int n = 0; n < 10; ++n) out[(size_t)row * 10 + n] = p[n] + bs[n];
  }
}

extern "C" void kernel_launch(void* const* d_in, const int* in_sizes, int n_in,
                              void* d_out, int out_size, void* d_ws, size_t ws_size,
                              hipStream_t stream) {
  const float* x_author = (const float*)d_in[0];
  const float* x_paper  = (const float*)d_in[1];
  const int* ei_a2p = (const int*)d_in[2];
  const int* ei_p2a = (const int*)d_in[3];
  const int* src_ap = ei_a2p;       // author indices
  const int* dst_ap = ei_a2p + NE;  // paper indices
  const int* src_pa = ei_p2a;       // paper indices
  const int* dst_pa = ei_p2a + NE;  // author indices
  const float* Wl0_ap = (const float*)d_in[4];
  const float* bl0_ap = (const float*)d_in[5];
  const float* Wr0_ap = (const float*)d_in[6];
  const float* br0_ap = (const float*)d_in[7];
  const float* Wl0_pa = (const float*)d_in[8];
  const float* bl0_pa = (const float*)d_in[9];
  const float* Wr0_pa = (const float*)d_in[10];
  const float* br0_pa = (const float*)d_in[11];
  const float* Wl_ap = (const float*)d_in[12];
  const float* bl_ap = (const float*)d_in[13];
  const float* Wr_ap = (const float*)d_in[14];
  const float* br_ap = (const float*)d_in[15];
  const float* Wl_pa = (const float*)d_in[16];
  const float* bl_pa = (const float*)d_in[17];
  const float* Wr_pa = (const float*)d_in[18];
  const float* br_pa = (const float*)d_in[19];
  const float* W_out = (const float*)d_in[20];
  const float* b_out = (const float*)d_in[21];
  float* out = (float*)d_out;

  // ---- workspace layout (byte offsets, 256B-aligned chunks) ----
  char* base = (char*)d_ws;
  size_t o = 0;
  auto alloc = [&](size_t bytes) {
    void* p = base + o;
    o += (bytes + 255) & ~(size_t)255;
    return p;
  };
  u16* paper   = (u16*)alloc((size_t)NP * 256 * 2);
  u16* author  = (u16*)alloc((size_t)NA * 256 * 2);
  u16* paper2  = (u16*)alloc((size_t)NP * 256 * 2);
  u16* author2 = (u16*)alloc((size_t)NA * 256 * 2);
  u16* xp_bf  = (u16*)alloc((size_t)NP * 256 * 2);
  u16* xa_bf  = (u16*)alloc((size_t)NA * 128 * 2);
  u16* wc0_p = (u16*)alloc((128 + 256) * 256 * 2);        // [Wl0_ap | Wr0_ap]
  u16* wc0_a = (u16*)alloc((256 + 128) * 256 * 2);        // [Wl0_pa | Wr0_pa]
  u16* wc_ap = (u16*)alloc((size_t)2 * 512 * 256 * 2);    // per layer: [Wl | Wr]
  u16* wc_pa = (u16*)alloc((size_t)2 * 512 * 256 * 2);
  float* bias0_ap = (float*)alloc(256 * 4);
  float* bias0_pa = (float*)alloc(256 * 4);
  float* bias_ap  = (float*)alloc(2 * 256 * 4);
  float* bias_pa  = (float*)alloc(2 * 256 * 4);
  int* cnt_p  = (int*)alloc((size_t)(NP + NA) * 4);  // cnt_p + cnt_a contiguous
  int* cnt_a  = cnt_p + NP;
  int* rs_p   = (int*)alloc((size_t)(NP + 1) * 4);
  int* rs_a   = (int*)alloc((size_t)(NA + 1) * 4);
  int* cur_p  = (int*)alloc((size_t)NP * 4);
  int* cur_a  = (int*)alloc((size_t)NA * 4);
  int* csrc_p = (int*)alloc((size_t)NE * 4);
  int* csrc_a = (int*)alloc((size_t)NE * 4);
  int* bsum_p = (int*)alloc(128 * 4);
  int* bsum_a = (int*)alloc(128 * 4);

  const int NBP = (NP + SCAN_CHUNK - 1) / SCAN_CHUNK;  // 98
  const int NBA = (NA + SCAN_CHUNK - 1) / SCAN_CHUNK;  // 49

  // ---- CSR build (once, reused by all 3 layers) ----
  hipMemsetAsync(cnt_p, 0, (size_t)(NP + NA) * 4, stream);
  count_deg_i<<<(2 * NE + 255) / 256, 256, 0, stream>>>(dst_ap, dst_pa, cnt_p, cnt_a);
  block_sums_k<<<NBP, 256, 0, stream>>>(cnt_p, bsum_p, NP);
  block_sums_k<<<NBA, 256, 0, stream>>>(cnt_a, bsum_a, NA);
  scan_bsums_k<<<1, 256, 0, stream>>>(bsum_p, NBP);
  scan_bsums_k<<<1, 256, 0, stream>>>(bsum_a, NBA);
  scan_final_k<<<NBP, 256, 0, stream>>>(cnt_p, bsum_p, rs_p, cur_p, NP, NE);
  scan_final_k<<<NBA, 256, 0, stream>>>(cnt_a, bsum_a, rs_a, cur_a, NA, NE);
  csr_fill<<<(NE + 255) / 256, 256, 0, stream>>>(src_ap, dst_ap, cur_p, csrc_p);
  csr_fill<<<(NE + 255) / 256, 256, 0, stream>>>(src_pa, dst_pa, cur_a, csrc_a);

  // ---- input conversion to bf16 ----
  to_bf16<<<((NP * 256 / 4) + 255) / 256, 256, 0, stream>>>(x_paper, xp_bf, NP * 256 / 4);
  to_bf16<<<((NA * 128 / 4) + 255) / 256, 256, 0, stream>>>(x_author, xa_bf, NA * 128 / 4);

  // ---- weight pack (single launch) ----
  {
    PackJobs J;
    const float* srcs[12] = {Wl0_ap, Wr0_ap, Wl0_pa, Wr0_pa,
                             Wl_ap, Wr_ap, Wl_pa, Wr_pa,
                             Wl_ap + 65536, Wr_ap + 65536, Wl_pa + 65536, Wr_pa + 65536};
    u16* dsts[12] = {wc0_p, wc0_p + 128 * 256, wc0_a, wc0_a + 256 * 256,
                     wc_ap, wc_ap + 65536, wc_pa, wc_pa + 65536,
                     wc_ap + 131072, wc_ap + 131072 + 65536,
                     wc_pa + 131072, wc_pa + 131072 + 65536};
    int Ks[12] = {128, 256, 256, 128, 256, 256, 256, 256, 256, 256, 256, 256};
    int off = 0;
    for (int j = 0; j < 12; ++j) {
      J.src[j] = srcs[j];
      J.dst[j] = dsts[j];
      J.K[j] = Ks[j];
      J.boff[j] = off;
      off += Ks[j] / 8;
    }
    J.boff[12] = off;
    pack_all<<<off, 256, 0, stream>>>(J);
  }
  // ---- bias combine (single launch) ----
  {
    BiasJobs J;
    const float* as[6] = {bl0_ap, bl0_pa, bl_ap, bl_ap + 256, bl_pa, bl_pa + 256};
    const float* bs[6] = {br0_ap, br0_pa, br_ap, br_ap + 256, br_pa, br_pa + 256};
    float* os[6] = {bias0_ap, bias0_pa, bias_ap, bias_ap + 256, bias_pa, bias_pa + 256};
    for (int j = 0; j < 6; ++j) { J.a[j] = as[j]; J.b[j] = bs[j]; J.o[j] = os[j]; }
    bias_all<<<6, 256, 0, stream>>>(J);
  }

  // fused-layer grids: 128 rows x 256 cols per block
  const int nbP = (NP + 127) / 128;  // 782
  const int nbA = (NA + 127) / 128;  // 391

  // ---- layer 0: (x_author 128, x_paper 256) -> paper, author ----
  sage_fgem<<<nbP + nbA, 512, 0, stream>>>(
      SideF{xa_bf, csrc_p, rs_p, xp_bf, wc0_p, bias0_ap, paper, NP, 128, 256},
      SideF{xp_bf, csrc_a, rs_a, xa_bf, wc0_a, bias0_pa, author, NA, 256, 128}, nbP);

  // ---- layer 1: (paper, author) -> (paper2, author2) ----
  sage_fgem<<<nbP + nbA, 512, 0, stream>>>(
      SideF{author, csrc_p, rs_p, paper, wc_ap, bias_ap, paper2, NP, 256, 256},
      SideF{paper, csrc_a, rs_a, author, wc_pa, bias_pa, author2, NA, 256, 256}, nbP);

  // ---- layer 2: author side ONLY (paper side of the last layer is dead code:
  //      the reference returns author @ W_out; final paper is never consumed) ----
  sage_fgem<<<nbA, 512, 0, stream>>>(
      SideF{paper2, csrc_a, rs_a, author2, wc_pa + 131072, bias_pa + 256, author, NA, 256, 256},
      SideF{paper2, csrc_a, rs_a, author2, wc_pa + 131072, bias_pa + 256, author, NA, 256, 256}, 0);

  // ---- output projection ----
  out_proj<<<(NA + 3) / 4, 256, 0, stream>>>(author, W_out, b_out, out, NA);
}

// Round 14
// 463.583 us; speedup vs baseline: 1.5339x; 1.5339x over previous
//
#include <hip/hip_runtime.h>
#include <hip/hip_bf16.h>
#include <cstddef>

#define NA 50000
#define NP 100000
#define NE 200000
#define SCAN_CHUNK 1024

typedef unsigned short u16;
typedef unsigned int u32;
typedef short v8s __attribute__((ext_vector_type(8)));
typedef float f32x4 __attribute__((ext_vector_type(4)));

__device__ __forceinline__ float elu_f(float x) {
  return x > 0.0f ? x : expm1f(x);
}
__device__ __forceinline__ u16 f2bf(float x) {
  u32 u = __float_as_uint(x);
  return (u16)((u + 0x7fffu + ((u >> 16) & 1u)) >> 16);
}
__device__ __forceinline__ float bf2f(u16 h) {
  return __uint_as_float(((u32)h) << 16);
}
__device__ __forceinline__ u32 pk2(float a, float b) {
  return (u32)f2bf(a) | ((u32)f2bf(b) << 16);
}
__device__ __forceinline__ float lo_f(u32 w) { return __uint_as_float(w << 16); }
__device__ __forceinline__ float hi_f(u32 w) { return __uint_as_float(w & 0xffff0000u); }

// async global->LDS, 16B per lane; ldst must be wave-uniform (HW adds lane*16)
__device__ __forceinline__ void gload_lds16(const u16* gsrc, u16* ldst) {
  __builtin_amdgcn_global_load_lds(
      (const __attribute__((address_space(1))) u32*)gsrc,
      (__attribute__((address_space(3))) u32*)ldst, 16, 0, 0);
}

// ---------------- degree counting (int) ----------------
__global__ void count_deg_i(const int* __restrict__ dst_p, const int* __restrict__ dst_a,
                            int* cnt_p, int* cnt_a) {
  int i = blockIdx.x * blockDim.x + threadIdx.x;
  if (i < NE) atomicAdd(&cnt_p[dst_p[i]], 1);
  else if (i < 2 * NE) atomicAdd(&cnt_a[dst_a[i - NE]], 1);
}

// ---------------- 3-kernel exclusive scan ----------------
__global__ void block_sums_k(const int* __restrict__ cnt, int* __restrict__ bsums, int n) {
  __shared__ int red[256];
  int t = threadIdx.x;
  int base = blockIdx.x * SCAN_CHUNK + t * 4;
  int s = 0;
  #pragma unroll
  for (int i = 0; i < 4; ++i) {
    int idx = base + i;
    if (idx < n) s += cnt[idx];
  }
  red[t] = s;
  __syncthreads();
  for (int off = 128; off > 0; off >>= 1) {
    if (t < off) red[t] += red[t + off];
    __syncthreads();
  }
  if (t == 0) bsums[blockIdx.x] = red[0];
}

__global__ void scan_bsums_k(int* bsums, int nb) {  // nb <= 256, single block
  __shared__ int tmp[256];
  int t = threadIdx.x;
  int orig = (t < nb) ? bsums[t] : 0;
  tmp[t] = orig;
  __syncthreads();
  for (int off = 1; off < 256; off <<= 1) {
    int u = (t >= off) ? tmp[t - off] : 0;
    __syncthreads();
    tmp[t] += u;
    __syncthreads();
  }
  if (t < nb) bsums[t] = tmp[t] - orig;  // exclusive
}

// writes row_start AND cursor copy
__global__ void scan_final_k(const int* __restrict__ cnt, const int* __restrict__ bsums,
                             int* __restrict__ row_start, int* __restrict__ cursor,
                             int n, int total) {
  __shared__ int red[256];
  int t = threadIdx.x;
  int base = blockIdx.x * SCAN_CHUNK + t * 4;
  int v[4];
  int s = 0;
  #pragma unroll
  for (int i = 0; i < 4; ++i) {
    int idx = base + i;
    v[i] = (idx < n) ? cnt[idx] : 0;
    s += v[i];
  }
  int orig = s;
  red[t] = s;
  __syncthreads();
  for (int off = 1; off < 256; off <<= 1) {
    int u = (t >= off) ? red[t - off] : 0;
    __syncthreads();
    red[t] += u;
    __syncthreads();
  }
  int excl = red[t] - orig + bsums[blockIdx.x];
  #pragma unroll
  for (int i = 0; i < 4; ++i) {
    int idx = base + i;
    if (idx < n) {
      row_start[idx] = excl;
      cursor[idx] = excl;
    }
    excl += v[i];
  }
  if (blockIdx.x == 0 && t == 0) row_start[n] = total;
}

__global__ void csr_fill(const int* __restrict__ src, const int* __restrict__ dst,
                         int* cursor, int* __restrict__ csr_src) {
  int e = blockIdx.x * blockDim.x + threadIdx.x;
  if (e < NE) {
    int p = atomicAdd(&cursor[dst[e]], 1);
    csr_src[p] = src[e];
  }
}

// ---------------- f32 -> bf16 bulk convert ----------------
__global__ void to_bf16(const float* __restrict__ in, u16* __restrict__ out, int n4) {
  int i = blockIdx.x * 256 + threadIdx.x;
  if (i >= n4) return;
  float4 v = ((const float4*)in)[i];
  uint2 o;
  o.x = pk2(v.x, v.y);
  o.y = pk2(v.z, v.w);
  *(uint2*)(out + (size_t)i * 4) = o;
}

// ---------------- weight pack (all matrices, one launch) ----------------
// W: [256][K] f32 -> Wp[ks][c 16][lane 64][8] bf16
struct PackJobs {
  const float* src[12];
  u16* dst[12];
  int K[12];
  int boff[13];
};

__global__ void pack_all(PackJobs J) {
  int blk = blockIdx.x;
  int j = 0;
  while (j < 11 && blk >= J.boff[j + 1]) ++j;
  int id = (blk - J.boff[j]) * 256 + threadIdx.x;  // < K*32 exactly
  int K = J.K[j];
  int l = id & 63;
  int c = (id >> 6) & 15;
  int ks = id >> 10;
  int n = c * 16 + (l & 15);
  int k = ks * 32 + (l >> 4) * 8;
  const float* src = J.src[j] + (size_t)n * K + k;
  uint4 o;
  o.x = pk2(src[0], src[1]);
  o.y = pk2(src[2], src[3]);
  o.z = pk2(src[4], src[5]);
  o.w = pk2(src[6], src[7]);
  *(uint4*)(J.dst[j] + (size_t)id * 8) = o;
}

// ---------------- bias combine (all 6, one launch) ----------------
struct BiasJobs {
  const float* a[6];
  const float* b[6];
  float* o[6];
};
__global__ void bias_all(BiasJobs J) {
  int j = blockIdx.x;
  int i = threadIdx.x;
  J.o[j][i] = J.a[j][i] + J.b[j][i];
}

// ---------------- gather-mean, half-wave (32 lanes) per node, 2-deep pipeline ----------------
template <int D>
__device__ __forceinline__ void gm_node(const u16* __restrict__ feat, const int* __restrict__ cs,
                                        const int* __restrict__ rs, u16* __restrict__ agg,
                                        int node, int lane) {
  int beg = rs[node], end = rs[node + 1];
  int deg = end - beg;
  if (D == 256) {  // 8 elems/lane, 16B loads
    float a0 = 0.f, a1 = 0.f, a2 = 0.f, a3 = 0.f, a4 = 0.f, a5 = 0.f, a6 = 0.f, a7 = 0.f;
    int e = beg;
    uint4 un = {0, 0, 0, 0};
    if (e < end) un = *(const uint4*)(feat + (size_t)cs[e] * 256 + lane * 8);
    while (e < end) {
      uint4 u = un;
      ++e;
      if (e < end)  // issue next row load before consuming current
        un = *(const uint4*)(feat + (size_t)cs[e] * 256 + lane * 8);
      a0 += lo_f(u.x); a1 += hi_f(u.x);
      a2 += lo_f(u.y); a3 += hi_f(u.y);
      a4 += lo_f(u.z); a5 += hi_f(u.z);
      a6 += lo_f(u.w); a7 += hi_f(u.w);
    }
    float inv = 1.0f / fmaxf((float)deg, 1.0f);
    uint4 o;
    o.x = pk2(a0 * inv, a1 * inv);
    o.y = pk2(a2 * inv, a3 * inv);
    o.z = pk2(a4 * inv, a5 * inv);
    o.w = pk2(a6 * inv, a7 * inv);
    *(uint4*)(agg + (size_t)node * 256 + lane * 8) = o;
  } else {  // D=128: 4 elems/lane, 8B loads
    float a0 = 0.f, a1 = 0.f, a2 = 0.f, a3 = 0.f;
    int e = beg;
    uint2 un = {0, 0};
    if (e < end) un = *(const uint2*)(feat + (size_t)cs[e] * 128 + lane * 4);
    while (e < end) {
      uint2 u = un;
      ++e;
      if (e < end)
        un = *(const uint2*)(feat + (size_t)cs[e] * 128 + lane * 4);
      a0 += lo_f(u.x); a1 += hi_f(u.x);
      a2 += lo_f(u.y); a3 += hi_f(u.y);
    }
    float inv = 1.0f / fmaxf((float)deg, 1.0f);
    uint2 o;
    o.x = pk2(a0 * inv, a1 * inv);
    o.y = pk2(a2 * inv, a3 * inv);
    *(uint2*)(agg + (size_t)node * 128 + lane * 4) = o;
  }
}

// fused gather for both node types in one dispatch (half-wave per node)
template <int D1, int D2>
__global__ __launch_bounds__(256) void gather2(
    const u16* __restrict__ f1, const int* __restrict__ cs1, const int* __restrict__ rs1,
    u16* __restrict__ a1, int n1,
    const u16* __restrict__ f2, const int* __restrict__ cs2, const int* __restrict__ rs2,
    u16* __restrict__ a2, int n2) {
  int hw = (blockIdx.x * 256 + threadIdx.x) >> 5;
  int lane = threadIdx.x & 31;
  if (hw < n1) gm_node<D1>(f1, cs1, rs1, a1, hw, lane);
  else if (hw - n1 < n2) gm_node<D2>(f2, cs2, rs2, a2, hw - n1, lane);
}

// ---------------- SAGE update: counted-vmcnt 3-buffer pipeline, x 2 stages ahead ----------------
// out[i,:] = elu( agg[i,:] @ Wl^T + x[i,:] @ Wr^T + bias ), Wp packed [Wl|Wr].
// Block: 512 thr = 8 waves; tile = 256 rows x 128 cols (cg = bid&1). Wave: 32 rows
// (2 x 16-row MFMA tiles) x 128 cols (8 ctiles), acc[2][8]. K-chunks of 32 (8 KB
// weight slices, 3 LDS buffers). Stage s issues EXACTLY {wstage(s+2), xload(s+2)x2}
// = 3 VMEM ops, then MFMAs on chunk s, then `s_waitcnt vmcnt(3)` + s_barrier: only
// this stage's 3 ops stay in flight, so ops for stage s+1 (issued at s-1) are
// complete with TWO full stages of latency cover. Prologue drains once (vmcnt(0))
// to avoid issue-order hazards on buffer 0. In-loop counting is order-independent
// within a stage (asm "memory" clobbers pin the 3 ops between barriers).
struct SideB {
  const u16* agg;
  const u16* x;
  const u16* Wp;     // packed, (K1+K2)*256 u16, chunk-major
  const float* bias;
  u16* out;
  int M;
  int K1;
  int K2;
};

template <int NK>
__global__ __launch_bounds__(512, 4) void sage_pipe(SideB P, SideB A, int nbP2) {
  __shared__ __align__(16) u16 ldsw[3 * 4096];  // 3 x 8 KB
  SideB S;
  int bid = blockIdx.x;
  if (bid < nbP2) { S = P; } else { bid -= nbP2; S = A; }
  const int cg = bid & 1;
  const int rg = bid >> 1;

  const int k1c = S.K1 >> 5;
  const int t = threadIdx.x;
  const int w = t >> 6, l = t & 63;
  const int lr = l & 15, lk = l >> 4;
  const int rowbase = rg * 256 + w * 32;

  int rowv[2];
  const u16 *pa[2], *px[2];
  #pragma unroll
  for (int rt = 0; rt < 2; ++rt) {
    int row = rowbase + rt * 16 + lr;
    rowv[rt] = row;
    int ar = min(row, S.M - 1);
    pa[rt] = S.agg + (size_t)ar * S.K1 + lk * 8;
    px[rt] = S.x + (size_t)ar * S.K2 + lk * 8;
  }

  auto xload = [&](int c, int rt) -> v8s {
    const u16* p = (c < k1c) ? (pa[rt] + c * 32) : (px[rt] + (c - k1c) * 32);
    return *(const v8s*)p;
  };
  // weight DMA for chunk c into LDS buffer b: per-lane global src, wave-uniform dest
  auto wstage = [&](int c, int b) {
    const u16* gsrc = S.Wp + ((size_t)c * 1024 + cg * 512 + t) * 8;
    u16* ldst = ldsw + b * 4096 + w * 512;  // wave-uniform (w uniform per wave)
    gload_lds16(gsrc, ldst);
  };

  f32x4 acc[2][8];
  #pragma unroll
  for (int rt = 0; rt < 2; ++rt)
    #pragma unroll
    for (int i = 0; i < 8; ++i) acc[rt][i] = (f32x4){0.f, 0.f, 0.f, 0.f};

  // prologue: buffers 0,1 + x for chunks 0,1; one-time full drain (safe vs reorder)
  v8s xc[2], xn[2], xn2[2];
  wstage(0, 0);
  wstage(1, 1);
  xc[0] = xload(0, 0);
  xc[1] = xload(0, 1);
  if (NK > 1) {
    xn[0] = xload(1, 0);
    xn[1] = xload(1, 1);
  }
  asm volatile("s_waitcnt vmcnt(0)" ::: "memory");
  __builtin_amdgcn_s_barrier();

  #pragma unroll
  for (int s = 0; s < NK; ++s) {
    const int cur = s % 3;
    if (s + 2 < NK) {  // exactly 3 VMEM ops this stage, all for stage s+2
      wstage(s + 2, (s + 2) % 3);
      xn2[0] = xload(s + 2, 0);
      xn2[1] = xload(s + 2, 1);
    }
    const u16* lw = ldsw + cur * 4096 + (size_t)l * 8;
    #pragma unroll
    for (int i = 0; i < 8; ++i) {
      v8s wf = *(const v8s*)(lw + i * 512);
      acc[0][i] = __builtin_amdgcn_mfma_f32_16x16x32_bf16(wf, xc[0], acc[0][i], 0, 0, 0);
      acc[1][i] = __builtin_amdgcn_mfma_f32_16x16x32_bf16(wf, xc[1], acc[1][i], 0, 0, 0);
    }
    if (s + 1 < NK) {
      if (s + 2 < NK) {
        asm volatile("s_waitcnt vmcnt(3)" ::: "memory");  // keep this stage's 3 in flight
      } else {
        asm volatile("s_waitcnt vmcnt(0)" ::: "memory");  // tail: nothing new issued
      }
      __builtin_amdgcn_s_barrier();
      xc[0] = xn[0];  xc[1] = xn[1];
      xn[0] = xn2[0]; xn[1] = xn2[1];
    }
  }

  // epilogue: bias + ELU + bf16 store (256 B contiguous per row per block half)
  const int colb = cg * 128 + lk * 4;
  #pragma unroll
  for (int rt = 0; rt < 2; ++rt) {
    if (rowv[rt] < S.M) {
      u16* orow = S.out + (size_t)rowv[rt] * 256 + colb;
      #pragma unroll
      for (int i = 0; i < 8; ++i) {
        f32x4 bv = *(const f32x4*)(S.bias + colb + i * 16);
        float e0 = elu_f(acc[rt][i][0] + bv[0]);
        float e1 = elu_f(acc[rt][i][1] + bv[1]);
        float e2 = elu_f(acc[rt][i][2] + bv[2]);
        float e3 = elu_f(acc[rt][i][3] + bv[3]);
        uint2 o;
        o.x = pk2(e0, e1);
        o.y = pk2(e2, e3);
        *(uint2*)(orow + i * 16) = o;
      }
    }
  }
}

// ---------------- output projection (bf16 author) ----------------
__global__ __launch_bounds__(256) void out_proj(const u16* __restrict__ author,
                                                const float* __restrict__ W,
                                                const float* __restrict__ b,
                                                float* __restrict__ out, int M) {
  __shared__ float ws[10 * 256];
  __shared__ float bs[10];
  int t = threadIdx.x;
  for (int i = t; i < 2560; i += 256) ws[i] = W[i];
  if (t < 10) bs[t] = b[t];
  __syncthreads();
  int wave = t >> 6, lane = t & 63;
  int row = blockIdx.x * 4 + wave;
  if (row >= M) return;
  ushort4 u = *(const ushort4*)(author + (size_t)row * 256 + lane * 4);
  float a0 = bf2f(u.x), a1 = bf2f(u.y), a2 = bf2f(u.z), a3 = bf2f(u.w);
  float p[10];
  #pragma unroll
  for (int n = 0; n < 10; ++n) {
    const float* wv = ws + n * 256 + lane * 4;
    p[n] = a0 * wv[0] + a1 * wv[1] + a2 * wv[2] + a3 * wv[3];
  }
  #pragma unroll
  for (int off = 32; off > 0; off >>= 1) {
    #pragma unroll
    for (int n = 0; n < 10; ++n) p[n] += __shfl_down(p[n], off);
  }
  if (lane == 0) {
    #pragma unroll
    for (int n = 0; n < 10; ++n) out[(size_t)row * 10 + n] = p[n] + bs[n];
  }
}

extern "C" void kernel_launch(void* const* d_in, const int* in_sizes, int n_in,
                              void* d_out, int out_size, void* d_ws, size_t ws_size,
                              hipStream_t stream) {
  const float* x_author = (const float*)d_in[0];
  const float* x_paper  = (const float*)d_in[1];
  const int* ei_a2p = (const int*)d_in[2];
  const int* ei_p2a = (const int*)d_in[3];
  const int* src_ap = ei_a2p;       // author indices
  const int* dst_ap = ei_a2p + NE;  // paper indices
  const int* src_pa = ei_p2a;       // paper indices
  const int* dst_pa = ei_p2a + NE;  // author indices
  const float* Wl0_ap = (const float*)d_in[4];
  const float* bl0_ap = (const float*)d_in[5];
  const float* Wr0_ap = (const float*)d_in[6];
  const float* br0_ap = (const float*)d_in[7];
  const float* Wl0_pa = (const float*)d_in[8];
  const float* bl0_pa = (const float*)d_in[9];
  const float* Wr0_pa = (const float*)d_in[10];
  const float* br0_pa = (const float*)d_in[11];
  const float* Wl_ap = (const float*)d_in[12];
  const float* bl_ap = (const float*)d_in[13];
  const float* Wr_ap = (const float*)d_in[14];
  const float* br_ap = (const float*)d_in[15];
  const float* Wl_pa = (const float*)d_in[16];
  const float* bl_pa = (const float*)d_in[17];
  const float* Wr_pa = (const float*)d_in[18];
  const float* br_pa = (const float*)d_in[19];
  const float* W_out = (const float*)d_in[20];
  const float* b_out = (const float*)d_in[21];
  float* out = (float*)d_out;

  // ---- workspace layout (byte offsets, 256B-aligned chunks) ----
  char* base = (char*)d_ws;
  size_t o = 0;
  auto alloc = [&](size_t bytes) {
    void* p = base + o;
    o += (bytes + 255) & ~(size_t)255;
    return p;
  };
  u16* paper   = (u16*)alloc((size_t)NP * 256 * 2);
  u16* author  = (u16*)alloc((size_t)NA * 256 * 2);
  u16* paper2  = (u16*)alloc((size_t)NP * 256 * 2);
  u16* author2 = (u16*)alloc((size_t)NA * 256 * 2);
  u16* agg_p  = (u16*)alloc((size_t)NP * 256 * 2);
  u16* agg_a  = (u16*)alloc((size_t)NA * 256 * 2);
  u16* xp_bf  = (u16*)alloc((size_t)NP * 256 * 2);
  u16* xa_bf  = (u16*)alloc((size_t)NA * 128 * 2);
  u16* wc0_p = (u16*)alloc((128 + 256) * 256 * 2);        // [Wl0_ap | Wr0_ap]
  u16* wc0_a = (u16*)alloc((256 + 128) * 256 * 2);        // [Wl0_pa | Wr0_pa]
  u16* wc_ap = (u16*)alloc((size_t)2 * 512 * 256 * 2);    // per layer: [Wl | Wr]
  u16* wc_pa = (u16*)alloc((size_t)2 * 512 * 256 * 2);
  float* bias0_ap = (float*)alloc(256 * 4);
  float* bias0_pa = (float*)alloc(256 * 4);
  float* bias_ap  = (float*)alloc(2 * 256 * 4);
  float* bias_pa  = (float*)alloc(2 * 256 * 4);
  int* cnt_p  = (int*)alloc((size_t)(NP + NA) * 4);  // cnt_p + cnt_a contiguous
  int* cnt_a  = cnt_p + NP;
  int* rs_p   = (int*)alloc((size_t)(NP + 1) * 4);
  int* rs_a   = (int*)alloc((size_t)(NA + 1) * 4);
  int* cur_p  = (int*)alloc((size_t)NP * 4);
  int* cur_a  = (int*)alloc((size_t)NA * 4);
  int* csrc_p = (int*)alloc((size_t)NE * 4);
  int* csrc_a = (int*)alloc((size_t)NE * 4);
  int* bsum_p = (int*)alloc(128 * 4);
  int* bsum_a = (int*)alloc(128 * 4);

  const int NBP = (NP + SCAN_CHUNK - 1) / SCAN_CHUNK;  // 98
  const int NBA = (NA + SCAN_CHUNK - 1) / SCAN_CHUNK;  // 49

  // ---- CSR build (once, reused by all 3 layers) ----
  hipMemsetAsync(cnt_p, 0, (size_t)(NP + NA) * 4, stream);
  count_deg_i<<<(2 * NE + 255) / 256, 256, 0, stream>>>(dst_ap, dst_pa, cnt_p, cnt_a);
  block_sums_k<<<NBP, 256, 0, stream>>>(cnt_p, bsum_p, NP);
  block_sums_k<<<NBA, 256, 0, stream>>>(cnt_a, bsum_a, NA);
  scan_bsums_k<<<1, 256, 0, stream>>>(bsum_p, NBP);
  scan_bsums_k<<<1, 256, 0, stream>>>(bsum_a, NBA);
  scan_final_k<<<NBP, 256, 0, stream>>>(cnt_p, bsum_p, rs_p, cur_p, NP, NE);
  scan_final_k<<<NBA, 256, 0, stream>>>(cnt_a, bsum_a, rs_a, cur_a, NA, NE);
  csr_fill<<<(NE + 255) / 256, 256, 0, stream>>>(src_ap, dst_ap, cur_p, csrc_p);
  csr_fill<<<(NE + 255) / 256, 256, 0, stream>>>(src_pa, dst_pa, cur_a, csrc_a);

  // ---- input conversion to bf16 ----
  to_bf16<<<((NP * 256 / 4) + 255) / 256, 256, 0, stream>>>(x_paper, xp_bf, NP * 256 / 4);
  to_bf16<<<((NA * 128 / 4) + 255) / 256, 256, 0, stream>>>(x_author, xa_bf, NA * 128 / 4);

  // ---- weight pack (single launch) ----
  {
    PackJobs J;
    const float* srcs[12] = {Wl0_ap, Wr0_ap, Wl0_pa, Wr0_pa,
                             Wl_ap, Wr_ap, Wl_pa, Wr_pa,
                             Wl_ap + 65536, Wr_ap + 65536, Wl_pa + 65536, Wr_pa + 65536};
    u16* dsts[12] = {wc0_p, wc0_p + 128 * 256, wc0_a, wc0_a + 256 * 256,
                     wc_ap, wc_ap + 65536, wc_pa, wc_pa + 65536,
                     wc_ap + 131072, wc_ap + 131072 + 65536,
                     wc_pa + 131072, wc_pa + 131072 + 65536};
    int Ks[12] = {128, 256, 256, 128, 256, 256, 256, 256, 256, 256, 256, 256};
    int off = 0;
    for (int j = 0; j < 12; ++j) {
      J.src[j] = srcs[j];
      J.dst[j] = dsts[j];
      J.K[j] = Ks[j];
      J.boff[j] = off;
      off += Ks[j] / 8;
    }
    J.boff[12] = off;
    pack_all<<<off, 256, 0, stream>>>(J);
  }
  // ---- bias combine (single launch) ----
  {
    BiasJobs J;
    const float* as[6] = {bl0_ap, bl0_pa, bl_ap, bl_ap + 256, bl_pa, bl_pa + 256};
    const float* bs[6] = {br0_ap, br0_pa, br_ap, br_ap + 256, br_pa, br_pa + 256};
    float* os[6] = {bias0_ap, bias0_pa, bias_ap, bias_ap + 256, bias_pa, bias_pa + 256};
    for (int j = 0; j < 6; ++j) { J.a[j] = as[j]; J.b[j] = bs[j]; J.o[j] = os[j]; }
    bias_all<<<6, 256, 0, stream>>>(J);
  }

  // grid: 256 rows x 128 cols per block; adjacent cg siblings (R10/R12 layout)
  const int nbP2 = ((NP + 255) / 256) * 2;              // 782
  const int nbA2 = ((NA + 255) / 256) * 2;              // 392
  const int grid_sage = nbP2 + nbA2;                    // 1174
  const int grid_gath = (NP + NA) / 8;                  // 18750 (half-wave per node)

  // ---- layer 0 (author:128, paper:256 inputs) -> paper, author ----
  gather2<128, 256><<<grid_gath, 256, 0, stream>>>(
      xa_bf, csrc_p, rs_p, agg_p, NP, xp_bf, csrc_a, rs_a, agg_a, NA);
  sage_pipe<12><<<grid_sage, 512, 0, stream>>>(
      SideB{agg_p, xp_bf, wc0_p, bias0_ap, paper, NP, 128, 256},
      SideB{agg_a, xa_bf, wc0_a, bias0_pa, author, NA, 256, 128}, nbP2);

  // ---- layer 1: (paper, author) -> (paper2, author2) ----
  gather2<256, 256><<<grid_gath, 256, 0, stream>>>(
      author, csrc_p, rs_p, agg_p, NP, paper, csrc_a, rs_a, agg_a, NA);
  sage_pipe<16><<<grid_sage, 512, 0, stream>>>(
      SideB{agg_p, paper, wc_ap, bias_ap, paper2, NP, 256, 256},
      SideB{agg_a, author, wc_pa, bias_pa, author2, NA, 256, 256}, nbP2);

  // ---- layer 2: AUTHOR SIDE ONLY (final paper is dead code — the reference
  //      returns author @ W_out; paper from the last layer is never consumed) ----
  gather2<256, 256><<<(NA + 7) / 8, 256, 0, stream>>>(
      paper2, csrc_a, rs_a, agg_a, NA, paper2, csrc_a, rs_a, agg_a, 0);
  sage_pipe<16><<<nbA2, 512, 0, stream>>>(
      SideB{agg_a, author2, wc_pa + 131072, bias_pa + 256, author, NA, 256, 256},
      SideB{agg_a, author2, wc_pa + 131072, bias_pa + 256, author, NA, 256, 256}, 0);

  // ---- output projection ----
  out_proj<<<(NA + 3) / 4, 256, 0, stream>>>(author, W_out, b_out, out, NA);
}